// Round 8
// baseline (72.934 us; speedup 1.0000x reference)
//
#include <hip/hip_runtime.h>
#include <math.h>

// CircleLoss (m=1, GAMMA=1), stable online log-sum-exp:
//   loss = softplus(Mp + log Sp + Mn + log Sn)
// Memory-bound streaming reduce: 402 MB read once.
// Ladder: R2 80.8us (baseline wave/row, 5.0 TB/s) / R3-R4 structure-neutral /
// R5 fused atomics -94us (reverted) / R7 nt on p+n: 72.1us (5.6 TB/s), but
// FETCH unchanged at 197MB -> nt didn't move HBM traffic; gain = L2 pressure
// relief. R8: nt on ALL streams. Discriminates "composite delivery ceiling
// ~5.6 TB/s" (dur ~72, FETCH ~197) vs "HBM-direct streaming" (FETCH ~400,
// dur ~64). If unchanged -> roofline.

#define NEG_BIG (-1.0e30f)

typedef float vf4 __attribute__((ext_vector_type(4)));

__device__ __forceinline__ float margin_val(const void* p) {
    int iv = *(const int*)p;
    if (iv > -(1 << 23) && iv < (1 << 23)) return (float)iv;
    return *(const float*)p;
}

__device__ __forceinline__ float dot8(vf4 a0, vf4 a1, vf4 b0, vf4 b1) {
    return a0.x*b0.x + a0.y*b0.y + a0.z*b0.z + a0.w*b0.w
         + a1.x*b1.x + a1.y*b1.y + a1.z*b1.z + a1.w*b1.w;
}

// Combine two (max, scaled-sum) logsumexp states. Safe with NEG_BIG sentinels.
__device__ __forceinline__ void lse_combine(float& m, float& s, float om, float os) {
    float M = fmaxf(m, om);
    s = s * expf(m - M) + os * expf(om - M);
    m = M;
}

__device__ __forceinline__ void lse_add(float& m, float& s, float a) {
    if (a > m) {
        s = s * expf(m - a) + 1.0f;
        m = a;
    } else {
        s += expf(a - m);
    }
}

__global__ __launch_bounds__(256) void circle_partial(
    const float* __restrict__ anchor,
    const float* __restrict__ positive,
    const float* __restrict__ negative,
    const void* __restrict__ margin_p,
    float4* __restrict__ ws,   // per-block (mp, sp, mn, sn)
    int N)
{
    const float m       = margin_val(margin_p);
    const float delta_p = 1.0f - m;
    const float delta_n = m;
    const float op      = 1.0f + m;
    const float on      = -m;

    const int lane   = threadIdx.x & 63;
    const int wid    = threadIdx.x >> 6;
    const int gwave  = blockIdx.x * 4 + wid;   // blockDim fixed 256
    const int nwaves = gridDim.x * 4;

    float mp = NEG_BIG, sp = 0.0f;
    float mn = NEG_BIG, sn = 0.0f;

    // One wave per row: 64 lanes x 2 vf4 = 512 floats, fully coalesced.
    for (int row = gwave; row < N; row += nwaves) {
        const vf4* a4 = (const vf4*)(anchor   + (size_t)row * 512);
        const vf4* p4 = (const vf4*)(positive + (size_t)row * 512);
        const vf4* n4 = (const vf4*)(negative + (size_t)row * 512);

        // All streams nontemporal: single-touch data, keep it out of the
        // cache-allocation path entirely.
        vf4 a0 = __builtin_nontemporal_load(&a4[lane]);
        vf4 a1 = __builtin_nontemporal_load(&a4[lane + 64]);
        vf4 p0 = __builtin_nontemporal_load(&p4[lane]);
        vf4 p1 = __builtin_nontemporal_load(&p4[lane + 64]);
        vf4 n0 = __builtin_nontemporal_load(&n4[lane]);
        vf4 n1 = __builtin_nontemporal_load(&n4[lane + 64]);

        float pos = dot8(a0, a1, p0, p1);
        float neg = dot8(a0, a1, n0, n1);

        #pragma unroll
        for (int off = 32; off > 0; off >>= 1) {
            pos += __shfl_xor(pos, off, 64);
            neg += __shfl_xor(neg, off, 64);
        }

        // All lanes hold identical row dots; keep identical LSE state per lane.
        lse_add(mp, sp, -fabsf(op - pos) * (pos - delta_p));
        lse_add(mn, sn,  fabsf(neg - on) * (neg - delta_n));
    }

    __shared__ float s_mp[4], s_sp[4], s_mn[4], s_sn[4];
    if (lane == 0) { s_mp[wid] = mp; s_sp[wid] = sp; s_mn[wid] = mn; s_sn[wid] = sn; }
    __syncthreads();
    if (threadIdx.x == 0) {
        float Mp = NEG_BIG, Sp = 0.0f, Mn = NEG_BIG, Sn = 0.0f;
        for (int i = 0; i < 4; ++i) {
            lse_combine(Mp, Sp, s_mp[i], s_sp[i]);
            lse_combine(Mn, Sn, s_mn[i], s_sn[i]);
        }
        ws[blockIdx.x] = make_float4(Mp, Sp, Mn, Sn);  // plain overwrite
    }
}

__global__ __launch_bounds__(256) void circle_final(
    const float4* __restrict__ ws,
    int nblk,
    float* __restrict__ out)
{
    float mp = NEG_BIG, sp = 0.0f;
    float mn = NEG_BIG, sn = 0.0f;
    for (int i = threadIdx.x; i < nblk; i += blockDim.x) {
        float4 v = ws[i];
        lse_combine(mp, sp, v.x, v.y);
        lse_combine(mn, sn, v.z, v.w);
    }
    #pragma unroll
    for (int off = 32; off > 0; off >>= 1) {
        float omp = __shfl_xor(mp, off, 64);
        float osp = __shfl_xor(sp, off, 64);
        float omn = __shfl_xor(mn, off, 64);
        float osn = __shfl_xor(sn, off, 64);
        lse_combine(mp, sp, omp, osp);
        lse_combine(mn, sn, omn, osn);
    }
    __shared__ float s_mp[4], s_sp[4], s_mn[4], s_sn[4];
    const int lane = threadIdx.x & 63;
    const int wid  = threadIdx.x >> 6;
    if (lane == 0) { s_mp[wid] = mp; s_sp[wid] = sp; s_mn[wid] = mn; s_sn[wid] = sn; }
    __syncthreads();
    if (threadIdx.x == 0) {
        float Mp = NEG_BIG, Sp = 0.0f, Mn = NEG_BIG, Sn = 0.0f;
        for (int i = 0; i < 4; ++i) {
            lse_combine(Mp, Sp, s_mp[i], s_sp[i]);
            lse_combine(Mn, Sn, s_mn[i], s_sn[i]);
        }
        float L = Mp + Mn + logf(Sp) + logf(Sn);
        out[0] = fmaxf(L, 0.0f) + log1pf(expf(-fabsf(L)));
    }
}

extern "C" void kernel_launch(void* const* d_in, const int* in_sizes, int n_in,
                              void* d_out, int out_size, void* d_ws, size_t ws_size,
                              hipStream_t stream) {
    const float* anchor   = (const float*)d_in[0];
    const float* positive = (const float*)d_in[1];
    const float* negative = (const float*)d_in[2];
    const void*  margin   = d_in[3];

    const int N = in_sizes[0] >> 9;  // D = 512 per reference

    int nblk = 2048;  // 8 blocks/CU; 32 waves/CU resident; 8 rows per wave
    const size_t need = (size_t)nblk * sizeof(float4);
    if (ws_size < need) nblk = (int)(ws_size / sizeof(float4));

    circle_partial<<<nblk, 256, 0, stream>>>(anchor, positive, negative, margin,
                                             (float4*)d_ws, N);
    circle_final<<<1, 256, 0, stream>>>((const float4*)d_ws, nblk, (float*)d_out);
}